// Round 5
// baseline (642.168 us; speedup 1.0000x reference)
//
#include <hip/hip_runtime.h>
#include <math.h>

#define NLAYER 4
#define BB 4
#define SS 2048
#define DD 512
#define HH 8
#define DH 64
#define FF 2048
#define TT (BB*SS)      // 8192 tokens
#define LCH 64          // attention chunk length
#define NCH (SS/LCH)    // 32 chunks
#define LN_EPS 1e-5f
#define ATT_EPS 1e-6f

typedef __bf16 bf16x8 __attribute__((ext_vector_type(8)));
typedef float  f32x4  __attribute__((ext_vector_type(4)));

__device__ __forceinline__ unsigned short f2bf(float f) {
    union { float f; unsigned u; } a; a.f = f;
    unsigned u = a.u;
    unsigned r = (u + 0x7FFFu + ((u >> 16) & 1u)) >> 16;   // RNE
    return (unsigned short)r;
}
__device__ __forceinline__ float bf2f(unsigned short s) {
    union { unsigned u; float f; } a; a.u = ((unsigned)s) << 16;
    return a.f;
}
__device__ __forceinline__ float phi_f(float u) {   // elu(u)+1
    return u > 0.f ? u + 1.f : __expf(u);
}

// ---------------- lengths ----------------
__global__ __launch_bounds__(64)
void len_kernel(const int* __restrict__ x, int* __restrict__ len) {
    const int b = blockIdx.x;
    int cnt = 0;
    for (int s = threadIdx.x; s < SS; s += 64) cnt += (x[b * SS + s] != 0);
    #pragma unroll
    for (int off = 32; off; off >>= 1) cnt += __shfl_xor(cnt, off);
    if (threadIdx.x == 0) len[b] = cnt;
}

// ---------------- embedding + positional ----------------
__global__ __launch_bounds__(256)
void embed_kernel(const int* __restrict__ x, const float* __restrict__ emb,
                  const float* __restrict__ pe, float* __restrict__ h,
                  unsigned short* __restrict__ h_bf) {
    int t = blockIdx.x * 256 + threadIdx.x;   // over TT*128 float4 slots
    int row = t >> 7;
    int q = t & 127;
    int tok = x[row];
    int s = row & (SS - 1);
    float4 e = ((const float4*)(emb + (size_t)tok * DD))[q];
    float4 p = ((const float4*)(pe + (size_t)s * DD))[q];
    float4 v; v.x = e.x + p.x; v.y = e.y + p.y; v.z = e.z + p.z; v.w = e.w + p.w;
    ((float4*)(h + (size_t)row * DD))[q] = v;
    ushort4 ub; ub.x = f2bf(v.x); ub.y = f2bf(v.y); ub.z = f2bf(v.z); ub.w = f2bf(v.w);
    ((ushort4*)(h_bf + (size_t)row * DD))[q] = ub;
}

// ---------------- transpose f32[R][C] -> bf16[C][R] ----------------
__global__ __launch_bounds__(256)
void transpose_cvt(const float* __restrict__ src, unsigned short* __restrict__ dst,
                   int R, int C, size_t srcLS, size_t dstLS) {
    __shared__ float tile[32][33];
    const int z = blockIdx.z;
    src += (size_t)z * srcLS;
    dst += (size_t)z * dstLS;
    const int c0 = blockIdx.x * 32, r0 = blockIdx.y * 32;
    const int tx = threadIdx.x & 31, ty = threadIdx.x >> 5;  // ty 0..7
    #pragma unroll
    for (int i = 0; i < 32; i += 8)
        tile[ty + i][tx] = src[(size_t)(r0 + ty + i) * C + c0 + tx];
    __syncthreads();
    #pragma unroll
    for (int i = 0; i < 32; i += 8)
        dst[(size_t)(c0 + ty + i) * R + r0 + tx] = f2bf(tile[tx][ty + i]);
}

__global__ __launch_bounds__(256)
void bias_concat(const float* __restrict__ bq, const float* __restrict__ bk,
                 const float* __restrict__ bv, float* __restrict__ bqkv) {
    int idx = blockIdx.x * 256 + threadIdx.x;
    if (idx >= NLAYER * 1536) return;
    int l = idx / 1536, n = idx % 1536;
    float v = n < 512 ? bq[l * 512 + n] : (n < 1024 ? bk[l * 512 + n - 512] : bv[l * 512 + n - 1024]);
    bqkv[idx] = v;
}

// ---------------- async global->LDS 16B ----------------
__device__ __forceinline__ void gll16(void* lds_ptr, const void* g_ptr) {
    __builtin_amdgcn_global_load_lds(
        (const __attribute__((address_space(1))) void*)g_ptr,
        (__attribute__((address_space(3))) void*)lds_ptr, 16, 0, 0);
}

// ---------------- 128x128 2-phase GEMM (N=512 shapes) ----------------
template<int RELU, int WF, int WB>
__global__ __launch_bounds__(256, 2)
void gemm_bt(const unsigned short* __restrict__ A, const unsigned short* __restrict__ Bt,
             const float* __restrict__ bias, float* __restrict__ Cf,
             unsigned short* __restrict__ Cb, int M, int N, int K) {
    __shared__ __align__(16) char lds[2 * 2 * 128 * 64 * 2];   // 64 KiB
    const int Nt = N >> 7;
    const int bid = blockIdx.x;
    const int swz = (bid & 7) * ((int)gridDim.x >> 3) + (bid >> 3);
    const int m0 = (swz / Nt) * 128;
    const int n0 = (swz % Nt) * 128;
    const int tid = threadIdx.x;
    const int w = tid >> 6, lane = tid & 63;
    const int wr = w >> 1, wc = w & 1;
    const int srow = lane >> 3, scc = lane & 7;

    f32x4 acc[4][4] = {};

    auto stage = [&](int buf, int k0) {
        char* base = lds + buf * 32768;
        #pragma unroll
        for (int op = 0; op < 2; ++op) {
            const unsigned short* G = op ? Bt : A;
            const int r0 = op ? n0 : m0;
            char* obase = base + op * 16384;
            #pragma unroll
            for (int i = 0; i < 4; ++i) {
                int ii = w * 4 + i;
                int row = ii * 8 + srow;
                int chunk = scc ^ (row & 7);
                gll16(obase + ii * 1024,
                      G + (size_t)(r0 + row) * K + k0 + chunk * 8);
            }
        }
    };

    stage(0, 0);
    const int nt = K >> 6;
    int buf = 0;
    const int g = lane >> 4;
    const int rA = wr * 64 + (lane & 15);
    const int rB = wc * 64 + (lane & 15);

    for (int kt = 0; kt < nt; ++kt) {
        __syncthreads();
        if (kt + 1 < nt) stage(buf ^ 1, (kt + 1) << 6);
        const char* pA = lds + buf * 32768;
        const char* pB = pA + 16384;
        bf16x8 af[4][2], bfr[4][2];
        #pragma unroll
        for (int m = 0; m < 4; ++m)
            #pragma unroll
            for (int kk = 0; kk < 2; ++kk) {
                int row = rA + m * 16;
                int c = (kk * 4 + g) ^ (row & 7);
                af[m][kk] = *(const bf16x8*)(pA + row * 128 + c * 16);
            }
        #pragma unroll
        for (int n = 0; n < 4; ++n)
            #pragma unroll
            for (int kk = 0; kk < 2; ++kk) {
                int row = rB + n * 16;
                int c = (kk * 4 + g) ^ (row & 7);
                bfr[n][kk] = *(const bf16x8*)(pB + row * 128 + c * 16);
            }
        #pragma unroll
        for (int kk = 0; kk < 2; ++kk)
            #pragma unroll
            for (int m = 0; m < 4; ++m)
                #pragma unroll
                for (int n = 0; n < 4; ++n)
                    acc[m][n] = __builtin_amdgcn_mfma_f32_16x16x32_bf16(
                        af[m][kk], bfr[n][kk], acc[m][n], 0, 0, 0);
        buf ^= 1;
    }

    const int col16 = lane & 15;
    const int rgrp = lane >> 4;
    #pragma unroll
    for (int n = 0; n < 4; ++n) {
        int col = n0 + wc * 64 + n * 16 + col16;
        float bi = bias[col];
        #pragma unroll
        for (int m = 0; m < 4; ++m) {
            int rowb = m0 + wr * 64 + m * 16 + rgrp * 4;
            #pragma unroll
            for (int r = 0; r < 4; ++r) {
                float v = acc[m][n][r] + bi;
                if (RELU) v = v > 0.f ? v : 0.f;
                if (WF) Cf[(size_t)(rowb + r) * N + col] = v;
                if (WB) Cb[(size_t)(rowb + r) * N + col] = f2bf(v);
            }
        }
    }
}

// ---------------- 256x256 phase-split GEMM (QKV / FFN1) ----------------
// 8 waves (2M x 4N), BK=64, per-wave output 128x64. Per K-tile: 4 phases of
// {ds_read quadrant (+B in ph0) | stage next tile (ph0:A, ph1:B) | bar |
//  setprio 16xMFMA | bar}; vmcnt(0) drain once per tile with 2-3 phases of
// MFMA slack (~1000cy) covering HBM latency.
template<int RELU, int WF, int WB>
__global__ __launch_bounds__(512, 2)
void gemm8p(const unsigned short* __restrict__ A, const unsigned short* __restrict__ Bt,
            const float* __restrict__ bias, float* __restrict__ Cf,
            unsigned short* __restrict__ Cb, int M, int N, int K) {
    __shared__ __align__(16) char lds[131072];   // 2 buffers x (A 32KB + B 32KB)
    const int Nt = N >> 8;
    const int bid = blockIdx.x;
    const int swz = (bid & 7) * ((int)gridDim.x >> 3) + (bid >> 3);
    const int m0 = (swz / Nt) * 256;
    const int n0 = (swz % Nt) * 256;
    const int tid = threadIdx.x;
    const int w = tid >> 6, lane = tid & 63;
    const int wr = w >> 2, wc = w & 3;          // 2M x 4N wave grid
    const int srow = lane >> 3, scc = lane & 7;
    const int g = lane >> 4, l16 = lane & 15;

    f32x4 acc[8][4] = {};

    auto stageA = [&](int buf, int k0) {
        char* base = lds + buf * 65536;
        #pragma unroll
        for (int i = 0; i < 4; ++i) {
            int ii = w * 4 + i;                  // 0..31 -> 256 rows
            int row = ii * 8 + srow;
            int chunk = scc ^ (row & 7);
            gll16(base + ii * 1024, A + (size_t)(m0 + row) * K + k0 + chunk * 8);
        }
    };
    auto stageB = [&](int buf, int k0) {
        char* base = lds + buf * 65536 + 32768;
        #pragma unroll
        for (int i = 0; i < 4; ++i) {
            int ii = w * 4 + i;
            int row = ii * 8 + srow;
            int chunk = scc ^ (row & 7);
            gll16(base + ii * 1024, Bt + (size_t)(n0 + row) * K + k0 + chunk * 8);
        }
    };

    stageA(0, 0); stageB(0, 0);
    asm volatile("s_waitcnt vmcnt(0)" ::: "memory");
    __builtin_amdgcn_s_barrier();
    __builtin_amdgcn_sched_barrier(0);

    const int nt = K >> 6;
    for (int t = 0; t < nt; ++t) {
        const int bufc = t & 1;
        const char* pA = lds + bufc * 65536;
        const char* pB = pA + 32768;
        // B fragments for the whole tile (read in phase 0)
        bf16x8 bfr[4][2];
        #pragma unroll
        for (int n = 0; n < 4; ++n)
            #pragma unroll
            for (int kk = 0; kk < 2; ++kk) {
                int row = wc * 64 + n * 16 + l16;
                bfr[n][kk] = *(const bf16x8*)(pB + row * 128 + (((kk * 4 + g) ^ (row & 7)) << 4));
            }
        #pragma unroll
        for (int p = 0; p < 4; ++p) {
            bf16x8 af[2][2];
            #pragma unroll
            for (int mi = 0; mi < 2; ++mi)
                #pragma unroll
                for (int kk = 0; kk < 2; ++kk) {
                    int row = wr * 128 + (p * 2 + mi) * 16 + l16;
                    af[mi][kk] = *(const bf16x8*)(pA + row * 128 + (((kk * 4 + g) ^ (row & 7)) << 4));
                }
            if (p == 0 && t + 1 < nt) stageA(bufc ^ 1, (t + 1) << 6);
            if (p == 1 && t + 1 < nt) stageB(bufc ^ 1, (t + 1) << 6);
            __builtin_amdgcn_s_barrier();          // phase-lock waves
            __builtin_amdgcn_s_setprio(1);
            #pragma unroll
            for (int kk = 0; kk < 2; ++kk)
                #pragma unroll
                for (int mi = 0; mi < 2; ++mi)
                    #pragma unroll
                    for (int n = 0; n < 4; ++n)
                        acc[p * 2 + mi][n] = __builtin_amdgcn_mfma_f32_16x16x32_bf16(
                            af[mi][kk], bfr[n][kk], acc[p * 2 + mi][n], 0, 0, 0);
            __builtin_amdgcn_s_setprio(0);
            if (p == 3) asm volatile("s_waitcnt vmcnt(0)" ::: "memory");  // next tile staged
            __builtin_amdgcn_s_barrier();          // tile/phase boundary
            __builtin_amdgcn_sched_barrier(0);     // pin next-tile ds_reads below
        }
    }

    #pragma unroll
    for (int n = 0; n < 4; ++n) {
        int col = n0 + wc * 64 + n * 16 + l16;
        float bi = bias[col];
        #pragma unroll
        for (int m = 0; m < 8; ++m) {
            int rowb = m0 + wr * 128 + m * 16 + g * 4;
            #pragma unroll
            for (int r = 0; r < 4; ++r) {
                float v = acc[m][n][r] + bi;
                if (RELU) v = v > 0.f ? v : 0.f;
                if (WF) Cf[(size_t)(rowb + r) * N + col] = v;
                if (WB) Cb[(size_t)(rowb + r) * N + col] = f2bf(v);
            }
        }
    }
}

// ---------------- attention pass A (MFMA): states = K^T V (bf16 out), ksum ----------------
__global__ __launch_bounds__(256)
void attn_chunk_sums(const unsigned short* __restrict__ qkv, const int* __restrict__ len,
                     unsigned short* __restrict__ states, float* __restrict__ ksum) {
    const int c = blockIdx.x & (NCH - 1);
    const int bh = blockIdx.x / NCH;
    const int b = bh >> 3, h = bh & 7;
    const int L = len[b];
    const int tid = threadIdx.x;
    const int w = tid >> 6, lane = tid & 63;
    __shared__ __align__(16) unsigned short Kt[64 * 64];   // [d][j], swizzled
    __shared__ __align__(16) unsigned short Vt[64 * 64];   // [e][j], swizzled
    __shared__ float ksumP[4][64];

    float kpart = 0.f;
    #pragma unroll 8
    for (int t = 0; t < 16; ++t) {
        const int jj = 4 * t + w;
        const int d = lane;
        const int sglob = c * 64 + jj;
        const unsigned short* base = qkv + (size_t)(b * SS + sglob) * 1536 + h * 64 + d;
        float kv = bf2f(base[512]);
        float kp = (sglob < L) ? phi_f(kv) : 0.f;
        kpart += kp;
        const int sw = (((jj >> 3) ^ (d & 7)) << 3) + (jj & 7);
        Kt[d * 64 + sw] = f2bf(kp);
        Vt[d * 64 + sw] = base[1024];
    }
    ksumP[w][lane] = kpart;
    __syncthreads();

    const int frow = w * 16 + (lane & 15);   // d-row of output
    const int g = lane >> 4;
    bf16x8 ak[2];
    #pragma unroll
    for (int kk = 0; kk < 2; ++kk)
        ak[kk] = *(const bf16x8*)&Kt[frow * 64 + (((kk * 4 + g) ^ (frow & 7)) << 3)];
    f32x4 oc[4] = {};
    #pragma unroll
    for (int ef = 0; ef < 4; ++ef) {
        int brow = ef * 16 + (lane & 15);
        #pragma unroll
        for (int kk = 0; kk < 2; ++kk) {
            bf16x8 bv = *(const bf16x8*)&Vt[brow * 64 + (((kk * 4 + g) ^ (brow & 7)) << 3)];
            oc[ef] = __builtin_amdgcn_mfma_f32_16x16x32_bf16(ak[kk], bv, oc[ef], 0, 0, 0);
        }
    }
    unsigned short* so = states + (size_t)blockIdx.x * 4096;
    #pragma unroll
    for (int ef = 0; ef < 4; ++ef)
        #pragma unroll
        for (int r = 0; r < 4; ++r) {
            int dd = w * 16 + g * 4 + r;
            int e = ef * 16 + (lane & 15);
            so[dd * 64 + e] = f2bf(oc[ef][r]);
        }
    if (w == 0) {
        float s = ksumP[0][lane] + ksumP[1][lane] + ksumP[2][lane] + ksumP[3][lane];
        ksum[(size_t)blockIdx.x * 64 + lane] = s;
    }
}

// ---------------- attention pass B: exclusive prefix over chunks (bf16 in/out) ----------------
__global__ __launch_bounds__(256)
void attn_prefix(const unsigned short* __restrict__ states, const float* __restrict__ ksum,
                 unsigned short* __restrict__ sprefix, float* __restrict__ kprefix) {
    const int bh = blockIdx.x >> 4;
    const int idx = (blockIdx.x & 15) * 256 + threadIdx.x;
    size_t base = (size_t)bh * NCH * 4096 + idx;
    float run = 0.f;
    #pragma unroll 4
    for (int cc = 0; cc < NCH; ++cc) {
        size_t o = base + (size_t)cc * 4096;
        float v = bf2f(states[o]);
        sprefix[o] = f2bf(run);
        run += v;
    }
    if ((blockIdx.x & 15) == 0 && threadIdx.x < 64) {
        size_t kb = (size_t)bh * NCH * 64 + threadIdx.x;
        float krun = 0.f;
        for (int cc = 0; cc < NCH; ++cc) {
            size_t o = kb + (size_t)cc * 64;
            float v = ksum[o];
            kprefix[o] = krun;
            krun += v;
        }
    }
}

// ---------------- attention pass C (MFMA): intra + inter, write bf16 ----------------
__global__ __launch_bounds__(256)
void attn_output(const unsigned short* __restrict__ qkv, const int* __restrict__ len,
                 const unsigned short* __restrict__ sprefix, const float* __restrict__ kprefix,
                 unsigned short* __restrict__ a_bf) {
    const int c = blockIdx.x & (NCH - 1);
    const int bh = blockIdx.x / NCH;
    const int b = bh >> 3, h = bh & 7;
    const int L = len[b];
    const int tid = threadIdx.x;
    const int w = tid >> 6, lane = tid & 63;

    __shared__ __align__(16) unsigned short Qb[64 * 64];    // [i][d] swizzled
    __shared__ __align__(16) unsigned short Kb[64 * 64];    // [j][d] swizzled; reused for out
    __shared__ __align__(16) unsigned short SpT[64 * 64];   // [e][d] swizzled
    __shared__ __align__(16) unsigned short Vt[64 * 64];    // [e][j] swizzled
    __shared__ __align__(16) unsigned short Amb[64 * 64];   // [i][j] swizzled
    __shared__ float zq[64];
    __shared__ float zinv[64];

    const float kspv = kprefix[(size_t)(bh * NCH + c) * 64 + lane];
    const unsigned short* Sp = sprefix + (size_t)(bh * NCH + c) * 4096;

    #pragma unroll 4
    for (int t = 0; t < 16; ++t) {
        const int jj = 4 * t + w;
        const int d = lane;
        const int sglob = c * 64 + jj;
        const unsigned short* base = qkv + (size_t)(b * SS + sglob) * 1536 + h * 64 + d;
        float qv = bf2f(base[0]), kv = bf2f(base[512]);
        float qp = phi_f(qv);
        float kp = (sglob < L) ? phi_f(kv) : 0.f;
        const int swr = (((d >> 3) ^ (jj & 7)) << 3) + (d & 7);   // row-major (jj, d)
        Qb[jj * 64 + swr] = f2bf(qp);
        Kb[jj * 64 + swr] = f2bf(kp);
        const int swt = (((jj >> 3) ^ (d & 7)) << 3) + (jj & 7);  // transposed (d, jj)
        Vt[d * 64 + swt] = base[1024];
        SpT[d * 64 + swt] = Sp[jj * 64 + d];                      // Sp[dstate=jj][e=d]
        float zc = qp * kspv;                                     // Q . kprefix
        #pragma unroll
        for (int off = 32; off; off >>= 1) zc += __shfl_xor(zc, off);
        if (lane == 0) zq[jj] = zc;
    }
    __syncthreads();

    const int frow = w * 16 + (lane & 15);
    const int g = lane >> 4;
    bf16x8 aq[2];
    #pragma unroll
    for (int kk = 0; kk < 2; ++kk)
        aq[kk] = *(const bf16x8*)&Qb[frow * 64 + (((kk * 4 + g) ^ (frow & 7)) << 3)];

    // phase 1: Am = Q K^T
    f32x4 am[4] = {};
    #pragma unroll
    for (int jf = 0; jf < 4; ++jf) {
        int brow = jf * 16 + (lane & 15);
        #pragma unroll
        for (int kk = 0; kk < 2; ++kk) {
            bf16x8 bk = *(const bf16x8*)&Kb[brow * 64 + (((kk * 4 + g) ^ (brow & 7)) << 3)];
            am[jf] = __builtin_amdgcn_mfma_f32_16x16x32_bf16(aq[kk], bk, am[jf], 0, 0, 0);
        }
    }

    // phase 2: mask, z row-sums, Amb store (bf16)
    float zl[4] = {0.f, 0.f, 0.f, 0.f};
    #pragma unroll
    for (int jf = 0; jf < 4; ++jf) {
        #pragma unroll
        for (int r = 0; r < 4; ++r) {
            int i = w * 16 + g * 4 + r;
            int j = jf * 16 + (lane & 15);
            float v = (j <= i) ? am[jf][r] : 0.f;
            zl[r] += v;
            Amb[i * 64 + (((j >> 3) ^ (i & 7)) << 3) + (j & 7)] = f2bf(v);
        }
    }
    #pragma unroll
    for (int r = 0; r < 4; ++r)
        #pragma unroll
        for (int off = 1; off < 16; off <<= 1) zl[r] += __shfl_xor(zl[r], off);
    #pragma unroll
    for (int r = 0; r < 4; ++r) {
        if ((lane & 15) == r) {
            int i = w * 16 + g * 4 + r;
            zinv[i] = 1.f / (zl[r] + zq[i] + ATT_EPS);
        }
    }

    // phase 4: out = Q*SpT^T + Am*Vt^T
    f32x4 oc[4] = {};
    #pragma unroll
    for (int ef = 0; ef < 4; ++ef) {
        int brow = ef * 16 + (lane & 15);
        #pragma unroll
        for (int kk = 0; kk < 2; ++kk) {
            bf16x8 bs = *(const bf16x8*)&SpT[brow * 64 + (((kk * 4 + g) ^ (brow & 7)) << 3)];
            oc[ef] = __builtin_amdgcn_mfma_f32_16x16x32_bf16(aq[kk], bs, oc[ef], 0, 0, 0);
        }
    }
    bf16x8 aam[2];
    #pragma unroll
    for (int kk = 0; kk < 2; ++kk)
        aam[kk] = *(const bf16x8*)&Amb[frow * 64 + (((kk * 4 + g) ^ (frow & 7)) << 3)];
    #pragma unroll
    for (int ef = 0; ef < 4; ++ef) {
        int brow = ef * 16 + (lane & 15);
        #pragma unroll
        for (int kk = 0; kk < 2; ++kk) {
            bf16x8 bv = *(const bf16x8*)&Vt[brow * 64 + (((kk * 4 + g) ^ (brow & 7)) << 3)];
            oc[ef] = __builtin_amdgcn_mfma_f32_16x16x32_bf16(aam[kk], bv, oc[ef], 0, 0, 0);
        }
    }

    __syncthreads();   // all waves done reading Kb -> reuse as out staging
    #pragma unroll
    for (int ef = 0; ef < 4; ++ef) {
        #pragma unroll
        for (int r = 0; r < 4; ++r) {
            int i = w * 16 + g * 4 + r;
            int e = ef * 16 + (lane & 15);
            float zi = zinv[i];
            Kb[i * 64 + (((e >> 3) ^ (i & 7)) << 3) + (e & 7)] = f2bf(oc[ef][r] * zi);
        }
    }
    __syncthreads();
    {
        unsigned short* dst = a_bf + (size_t)(b * SS + c * 64) * 512 + h * 64;
        #pragma unroll
        for (int u = 0; u < 2; ++u) {
            int cid = tid + u * 256;            // chunk id 0..511
            int row = cid >> 3, cb = cid & 7;
            int4 val = *(const int4*)&Kb[row * 64 + ((cb ^ (row & 7)) << 3)];
            *(int4*)(dst + (size_t)row * 512 + cb * 8) = val;
        }
    }
}

// ---------------- residual + LayerNorm (wave per row) ----------------
template<int ADD, int WB>
__global__ __launch_bounds__(64)
void ln_kernel(const float* __restrict__ hin, const float* __restrict__ add,
               const float* __restrict__ gw, const float* __restrict__ bw,
               float* __restrict__ hout, unsigned short* __restrict__ hbf) {
    const int row = blockIdx.x;
    const int lane = threadIdx.x;
    float v[8];
    const float* hp = hin + (size_t)row * DD;
    float s = 0.f;
    #pragma unroll
    for (int i = 0; i < 2; ++i) {
        int q = lane + i * 64;
        float4 a = ((const float4*)hp)[q];
        if (ADD) {
            float4 bb = ((const float4*)(add + (size_t)row * DD))[q];
            a.x += bb.x; a.y += bb.y; a.z += bb.z; a.w += bb.w;
        }
        v[i*4+0] = a.x; v[i*4+1] = a.y; v[i*4+2] = a.z; v[i*4+3] = a.w;
        s += a.x + a.y + a.z + a.w;
    }
    #pragma unroll
    for (int off = 32; off; off >>= 1) s += __shfl_xor(s, off);
    float mu = s * (1.f / 512.f);
    float sq = 0.f;
    #pragma unroll
    for (int i = 0; i < 8; ++i) { float d = v[i] - mu; sq += d * d; }
    #pragma unroll
    for (int off = 32; off; off >>= 1) sq += __shfl_xor(sq, off);
    float rs = 1.f / sqrtf(sq * (1.f / 512.f) + LN_EPS);
    #pragma unroll
    for (int i = 0; i < 2; ++i) {
        int q = lane + i * 64;
        float4 gv = ((const float4*)gw)[q];
        float4 bv = ((const float4*)bw)[q];
        float4 o;
        o.x = (v[i*4+0] - mu) * rs * gv.x + bv.x;
        o.y = (v[i*4+1] - mu) * rs * gv.y + bv.y;
        o.z = (v[i*4+2] - mu) * rs * gv.z + bv.z;
        o.w = (v[i*4+3] - mu) * rs * gv.w + bv.w;
        ((float4*)(hout + (size_t)row * DD))[q] = o;
        if (WB) {
            ushort4 ub; ub.x = f2bf(o.x); ub.y = f2bf(o.y); ub.z = f2bf(o.z); ub.w = f2bf(o.w);
            ((ushort4*)(hbf + (size_t)row * DD))[q] = ub;
        }
    }
}

// ---------------- host ----------------
extern "C" void kernel_launch(void* const* d_in, const int* in_sizes, int n_in,
                              void* d_out, int out_size, void* d_ws, size_t ws_size,
                              hipStream_t stream) {
    (void)in_sizes; (void)n_in; (void)out_size; (void)ws_size;
    const int*   x   = (const int*)d_in[0];
    const float* emb = (const float*)d_in[1];
    const float* pe  = (const float*)d_in[2];
    const float* Wq  = (const float*)d_in[3];
    const float* bq  = (const float*)d_in[4];
    const float* Wk  = (const float*)d_in[5];
    const float* bk  = (const float*)d_in[6];
    const float* Wv  = (const float*)d_in[7];
    const float* bv  = (const float*)d_in[8];
    const float* Wo  = (const float*)d_in[9];
    const float* bo  = (const float*)d_in[10];
    const float* W1  = (const float*)d_in[11];
    const float* b1  = (const float*)d_in[12];
    const float* W2  = (const float*)d_in[13];
    const float* b2  = (const float*)d_in[14];
    const float* g1  = (const float*)d_in[15];
    const float* be1 = (const float*)d_in[16];
    const float* g2  = (const float*)d_in[17];
    const float* be2 = (const float*)d_in[18];
    const float* gf  = (const float*)d_in[19];
    const float* bff = (const float*)d_in[20];
    float* out = (float*)d_out;

    char* ws = (char*)d_ws;
    size_t off = 0;
    auto alloc = [&](size_t bytes) -> void* {
        void* p = ws + off; off += (bytes + 255) & ~(size_t)255; return p;
    };
    int* len              = (int*)alloc(16);
    unsigned short* qkv_t = (unsigned short*)alloc((size_t)NLAYER * 1536 * 512 * 2);
    unsigned short* wo_t  = (unsigned short*)alloc((size_t)NLAYER * 512 * 512 * 2);
    unsigned short* w1_t  = (unsigned short*)alloc((size_t)NLAYER * 2048 * 512 * 2);
    unsigned short* w2_t  = (unsigned short*)alloc((size_t)NLAYER * 512 * 2048 * 2);
    float* bqkv           = (float*)alloc((size_t)NLAYER * 1536 * 4);
    float* h              = (float*)alloc((size_t)TT * 512 * 4);
    unsigned short* h_bf  = (unsigned short*)alloc((size_t)TT * 512 * 2);
    unsigned short* qkv   = (unsigned short*)alloc((size_t)TT * 1536 * 2);
    unsigned short* a_bf  = (unsigned short*)alloc((size_t)TT * 512 * 2);
    float* obuf           = (float*)alloc((size_t)TT * 512 * 4);
    unsigned short* y1_bf = (unsigned short*)alloc((size_t)TT * 2048 * 2);
    unsigned short* states  = (unsigned short*)alloc((size_t)32 * NCH * 4096 * 2);
    float* ksum           = (float*)alloc((size_t)32 * NCH * 64 * 4);
    unsigned short* sprefix = (unsigned short*)alloc((size_t)32 * NCH * 4096 * 2);
    float* kprefix        = (float*)alloc((size_t)32 * NCH * 64 * 4);

    len_kernel<<<BB, 64, 0, stream>>>(x, len);
    embed_kernel<<<(TT * 128) / 256, 256, 0, stream>>>(x, emb, pe, h, h_bf);

    dim3 tb(256);
    transpose_cvt<<<dim3(16, 16, NLAYER), tb, 0, stream>>>(Wq, qkv_t,             512, 512, (size_t)512*512, (size_t)1536*512);
    transpose_cvt<<<dim3(16, 16, NLAYER), tb, 0, stream>>>(Wk, qkv_t + 512*512,   512, 512, (size_t)512*512, (size_t)1536*512);
    transpose_cvt<<<dim3(16, 16, NLAYER), tb, 0, stream>>>(Wv, qkv_t + 1024*512,  512, 512, (size_t)512*512, (size_t)1536*512);
    transpose_cvt<<<dim3(16, 16, NLAYER), tb, 0, stream>>>(Wo, wo_t,              512, 512, (size_t)512*512, (size_t)512*512);
    transpose_cvt<<<dim3(64, 16, NLAYER), tb, 0, stream>>>(W1, w1_t,              512, 2048, (size_t)512*2048, (size_t)2048*512);
    transpose_cvt<<<dim3(16, 64, NLAYER), tb, 0, stream>>>(W2, w2_t,              2048, 512, (size_t)2048*512, (size_t)512*2048);
    bias_concat<<<(NLAYER * 1536 + 255) / 256, 256, 0, stream>>>(bq, bk, bv, bqkv);

    for (int l = 0; l < NLAYER; ++l) {
        gemm8p<0,0,1><<<(TT/256) * (1536/256), 512, 0, stream>>>(
            h_bf, qkv_t + (size_t)l*1536*512, bqkv + l*1536, nullptr, qkv, TT, 1536, 512);
        attn_chunk_sums<<<32 * NCH, 256, 0, stream>>>(qkv, len, states, ksum);
        attn_prefix<<<32 * 16, 256, 0, stream>>>(states, ksum, sprefix, kprefix);
        attn_output<<<32 * NCH, 256, 0, stream>>>(qkv, len, sprefix, kprefix, a_bf);
        gemm_bt<0,1,0><<<(TT/128) * (512/128), 256, 0, stream>>>(
            a_bf, wo_t + (size_t)l*512*512, bo + l*512, obuf, nullptr, TT, 512, 512);
        ln_kernel<1,1><<<TT, 64, 0, stream>>>(h, obuf, g1 + l*512, be1 + l*512, h, h_bf);
        gemm8p<1,0,1><<<(TT/256) * (2048/256), 512, 0, stream>>>(
            h_bf, w1_t + (size_t)l*2048*512, b1 + l*2048, nullptr, y1_bf, TT, 2048, 512);
        gemm_bt<0,1,0><<<(TT/128) * (512/128), 256, 0, stream>>>(
            y1_bf, w2_t + (size_t)l*512*2048, b2 + l*512, obuf, nullptr, TT, 512, 2048);
        ln_kernel<1,1><<<TT, 64, 0, stream>>>(h, obuf, g2 + l*512, be2 + l*512, h, h_bf);
    }
    ln_kernel<0,0><<<TT, 64, 0, stream>>>(h, nullptr, gf, bff, out, nullptr);
}

// Round 6
// 581.645 us; speedup vs baseline: 1.1041x; 1.1041x over previous
//
#include <hip/hip_runtime.h>
#include <math.h>

#define NLAYER 4
#define BB 4
#define SS 2048
#define DD 512
#define HH 8
#define DH 64
#define FF 2048
#define TT (BB*SS)      // 8192 tokens
#define LCH 64          // attention chunk length
#define NCH (SS/LCH)    // 32 chunks
#define LN_EPS 1e-5f
#define ATT_EPS 1e-6f

typedef __bf16 bf16x8 __attribute__((ext_vector_type(8)));
typedef float  f32x4  __attribute__((ext_vector_type(4)));
typedef float  f32x16 __attribute__((ext_vector_type(16)));

__device__ __forceinline__ unsigned short f2bf(float f) {
    union { float f; unsigned u; } a; a.f = f;
    unsigned u = a.u;
    unsigned r = (u + 0x7FFFu + ((u >> 16) & 1u)) >> 16;   // RNE
    return (unsigned short)r;
}
__device__ __forceinline__ float bf2f(unsigned short s) {
    union { unsigned u; float f; } a; a.u = ((unsigned)s) << 16;
    return a.f;
}
__device__ __forceinline__ float phi_f(float u) {   // elu(u)+1
    return u > 0.f ? u + 1.f : __expf(u);
}

// ---------------- lengths ----------------
__global__ __launch_bounds__(64)
void len_kernel(const int* __restrict__ x, int* __restrict__ len) {
    const int b = blockIdx.x;
    int cnt = 0;
    for (int s = threadIdx.x; s < SS; s += 64) cnt += (x[b * SS + s] != 0);
    #pragma unroll
    for (int off = 32; off; off >>= 1) cnt += __shfl_xor(cnt, off);
    if (threadIdx.x == 0) len[b] = cnt;
}

// ---------------- embedding + positional ----------------
__global__ __launch_bounds__(256)
void embed_kernel(const int* __restrict__ x, const float* __restrict__ emb,
                  const float* __restrict__ pe, float* __restrict__ h,
                  unsigned short* __restrict__ h_bf) {
    int t = blockIdx.x * 256 + threadIdx.x;   // over TT*128 float4 slots
    int row = t >> 7;
    int q = t & 127;
    int tok = x[row];
    int s = row & (SS - 1);
    float4 e = ((const float4*)(emb + (size_t)tok * DD))[q];
    float4 p = ((const float4*)(pe + (size_t)s * DD))[q];
    float4 v; v.x = e.x + p.x; v.y = e.y + p.y; v.z = e.z + p.z; v.w = e.w + p.w;
    ((float4*)(h + (size_t)row * DD))[q] = v;
    ushort4 ub; ub.x = f2bf(v.x); ub.y = f2bf(v.y); ub.z = f2bf(v.z); ub.w = f2bf(v.w);
    ((ushort4*)(h_bf + (size_t)row * DD))[q] = ub;
}

// ---------------- transpose f32[R][C] -> bf16[C][R] ----------------
__global__ __launch_bounds__(256)
void transpose_cvt(const float* __restrict__ src, unsigned short* __restrict__ dst,
                   int R, int C, size_t srcLS, size_t dstLS) {
    __shared__ float tile[32][33];
    const int z = blockIdx.z;
    src += (size_t)z * srcLS;
    dst += (size_t)z * dstLS;
    const int c0 = blockIdx.x * 32, r0 = blockIdx.y * 32;
    const int tx = threadIdx.x & 31, ty = threadIdx.x >> 5;  // ty 0..7
    #pragma unroll
    for (int i = 0; i < 32; i += 8)
        tile[ty + i][tx] = src[(size_t)(r0 + ty + i) * C + c0 + tx];
    __syncthreads();
    #pragma unroll
    for (int i = 0; i < 32; i += 8)
        dst[(size_t)(c0 + ty + i) * R + r0 + tx] = f2bf(tile[tx][ty + i]);
}

__global__ __launch_bounds__(256)
void bias_concat(const float* __restrict__ bq, const float* __restrict__ bk,
                 const float* __restrict__ bv, float* __restrict__ bqkv) {
    int idx = blockIdx.x * 256 + threadIdx.x;
    if (idx >= NLAYER * 1536) return;
    int l = idx / 1536, n = idx % 1536;
    float v = n < 512 ? bq[l * 512 + n] : (n < 1024 ? bk[l * 512 + n - 512] : bv[l * 512 + n - 1024]);
    bqkv[idx] = v;
}

// ---------------- async global->LDS 16B ----------------
__device__ __forceinline__ void gll16(void* lds_ptr, const void* g_ptr) {
    __builtin_amdgcn_global_load_lds(
        (const __attribute__((address_space(1))) void*)g_ptr,
        (__attribute__((address_space(3))) void*)lds_ptr, 16, 0, 0);
}

// ---------------- 128x128 2-phase GEMM, 32x32x16 MFMA inner ----------------
// C[M,N] = A[M,K] * Bt[N,K]^T + bias. 4 waves (2x2), each wave 64x64 output
// as 2x2 32x32 frags. A/B input layout: row = lane%32, k = kstep*16 + 8*(lane/32)+j.
// C/D layout (m74/m101 verified): col = lane&31, row = (reg&3)+8*(reg>>2)+4*(lane>>5).
template<int RELU, int WB>
__global__ __launch_bounds__(256, 2)
void gemm_bt(const unsigned short* __restrict__ A, const unsigned short* __restrict__ Bt,
             const float* __restrict__ bias, float* __restrict__ Cf,
             unsigned short* __restrict__ Cb, int M, int N, int K) {
    __shared__ __align__(16) char lds[2 * 2 * 128 * 64 * 2];   // 64 KiB
    const int Nt = N >> 7;
    const int bid = blockIdx.x;
    const int swz = (bid & 7) * ((int)gridDim.x >> 3) + (bid >> 3);
    const int m0 = (swz / Nt) * 128;
    const int n0 = (swz % Nt) * 128;
    const int tid = threadIdx.x;
    const int w = tid >> 6, lane = tid & 63;
    const int wr = w >> 1, wc = w & 1;
    const int srow = lane >> 3, scc = lane & 7;
    const int l32 = lane & 31, khalf = lane >> 5;

    f32x16 acc[2][2] = {};

    auto stage = [&](int buf, int k0) {
        char* base = lds + buf * 32768;
        #pragma unroll
        for (int op = 0; op < 2; ++op) {
            const unsigned short* G = op ? Bt : A;
            const int r0 = op ? n0 : m0;
            char* obase = base + op * 16384;
            #pragma unroll
            for (int i = 0; i < 4; ++i) {
                int ii = w * 4 + i;
                int row = ii * 8 + srow;
                int chunk = scc ^ (row & 7);
                gll16(obase + ii * 1024,
                      G + (size_t)(r0 + row) * K + k0 + chunk * 8);
            }
        }
    };

    stage(0, 0);
    const int nt = K >> 6;
    int buf = 0;
    const int rA = wr * 64 + l32;
    const int rB = wc * 64 + l32;

    for (int kt = 0; kt < nt; ++kt) {
        __syncthreads();
        if (kt + 1 < nt) stage(buf ^ 1, (kt + 1) << 6);
        const char* pA = lds + buf * 32768;
        const char* pB = pA + 16384;
        bf16x8 af[2][4], bfr[2][4];
        #pragma unroll
        for (int mf = 0; mf < 2; ++mf)
            #pragma unroll
            for (int kk = 0; kk < 4; ++kk) {
                int row = rA + mf * 32;
                int c = (kk * 2 + khalf) ^ (row & 7);
                af[mf][kk] = *(const bf16x8*)(pA + row * 128 + c * 16);
            }
        #pragma unroll
        for (int nf = 0; nf < 2; ++nf)
            #pragma unroll
            for (int kk = 0; kk < 4; ++kk) {
                int row = rB + nf * 32;
                int c = (kk * 2 + khalf) ^ (row & 7);
                bfr[nf][kk] = *(const bf16x8*)(pB + row * 128 + c * 16);
            }
        #pragma unroll
        for (int kk = 0; kk < 4; ++kk)
            #pragma unroll
            for (int mf = 0; mf < 2; ++mf)
                #pragma unroll
                for (int nf = 0; nf < 2; ++nf)
                    acc[mf][nf] = __builtin_amdgcn_mfma_f32_32x32x16_bf16(
                        af[mf][kk], bfr[nf][kk], acc[mf][nf], 0, 0, 0);
        buf ^= 1;
    }

    // epilogue: col = lane&31, row = (reg&3)+8*(reg>>2)+4*khalf
    #pragma unroll
    for (int nf = 0; nf < 2; ++nf) {
        int col = n0 + wc * 64 + nf * 32 + l32;
        float bi = bias[col];
        #pragma unroll
        for (int mf = 0; mf < 2; ++mf) {
            int rowb = m0 + wr * 64 + mf * 32 + 4 * khalf;
            #pragma unroll
            for (int reg = 0; reg < 16; ++reg) {
                int row = rowb + (reg & 3) + 8 * (reg >> 2);
                float v = acc[mf][nf][reg] + bi;
                if (RELU) v = v > 0.f ? v : 0.f;
                if (WB) Cb[(size_t)row * N + col] = f2bf(v);
                else    Cf[(size_t)row * N + col] = v;
            }
        }
    }
}

// ---------------- attention pass A (MFMA): states = K^T V (bf16 out), ksum ----------------
__global__ __launch_bounds__(256)
void attn_chunk_sums(const unsigned short* __restrict__ qkv, const int* __restrict__ len,
                     unsigned short* __restrict__ states, float* __restrict__ ksum) {
    const int c = blockIdx.x & (NCH - 1);
    const int bh = blockIdx.x / NCH;
    const int b = bh >> 3, h = bh & 7;
    const int L = len[b];
    const int tid = threadIdx.x;
    const int w = tid >> 6, lane = tid & 63;
    __shared__ __align__(16) unsigned short Kt[64 * 64];   // [d][j], swizzled
    __shared__ __align__(16) unsigned short Vt[64 * 64];   // [e][j], swizzled
    __shared__ float ksumP[4][64];

    float kpart = 0.f;
    #pragma unroll 8
    for (int t = 0; t < 16; ++t) {
        const int jj = 4 * t + w;
        const int d = lane;
        const int sglob = c * 64 + jj;
        const unsigned short* base = qkv + (size_t)(b * SS + sglob) * 1536 + h * 64 + d;
        float kv = bf2f(base[512]);
        float kp = (sglob < L) ? phi_f(kv) : 0.f;
        kpart += kp;
        const int sw = (((jj >> 3) ^ (d & 7)) << 3) + (jj & 7);
        Kt[d * 64 + sw] = f2bf(kp);
        Vt[d * 64 + sw] = base[1024];
    }
    ksumP[w][lane] = kpart;
    __syncthreads();

    const int frow = w * 16 + (lane & 15);   // d-row of output
    const int g = lane >> 4;
    bf16x8 ak[2];
    #pragma unroll
    for (int kk = 0; kk < 2; ++kk)
        ak[kk] = *(const bf16x8*)&Kt[frow * 64 + (((kk * 4 + g) ^ (frow & 7)) << 3)];
    f32x4 oc[4] = {};
    #pragma unroll
    for (int ef = 0; ef < 4; ++ef) {
        int brow = ef * 16 + (lane & 15);
        #pragma unroll
        for (int kk = 0; kk < 2; ++kk) {
            bf16x8 bv = *(const bf16x8*)&Vt[brow * 64 + (((kk * 4 + g) ^ (brow & 7)) << 3)];
            oc[ef] = __builtin_amdgcn_mfma_f32_16x16x32_bf16(ak[kk], bv, oc[ef], 0, 0, 0);
        }
    }
    unsigned short* so = states + (size_t)blockIdx.x * 4096;
    #pragma unroll
    for (int ef = 0; ef < 4; ++ef)
        #pragma unroll
        for (int r = 0; r < 4; ++r) {
            int dd = w * 16 + g * 4 + r;
            int e = ef * 16 + (lane & 15);
            so[dd * 64 + e] = f2bf(oc[ef][r]);
        }
    if (w == 0) {
        float s = ksumP[0][lane] + ksumP[1][lane] + ksumP[2][lane] + ksumP[3][lane];
        ksum[(size_t)blockIdx.x * 64 + lane] = s;
    }
}

// ---------------- attention pass B: exclusive prefix over chunks (bf16 in/out) ----------------
__global__ __launch_bounds__(256)
void attn_prefix(const unsigned short* __restrict__ states, const float* __restrict__ ksum,
                 unsigned short* __restrict__ sprefix, float* __restrict__ kprefix) {
    const int bh = blockIdx.x >> 4;
    const int idx = (blockIdx.x & 15) * 256 + threadIdx.x;
    size_t base = (size_t)bh * NCH * 4096 + idx;
    float run = 0.f;
    #pragma unroll 4
    for (int cc = 0; cc < NCH; ++cc) {
        size_t o = base + (size_t)cc * 4096;
        float v = bf2f(states[o]);
        sprefix[o] = f2bf(run);
        run += v;
    }
    if ((blockIdx.x & 15) == 0 && threadIdx.x < 64) {
        size_t kb = (size_t)bh * NCH * 64 + threadIdx.x;
        float krun = 0.f;
        for (int cc = 0; cc < NCH; ++cc) {
            size_t o = kb + (size_t)cc * 64;
            float v = ksum[o];
            kprefix[o] = krun;
            krun += v;
        }
    }
}

// ---------------- attention pass C (MFMA): intra + inter, write bf16 ----------------
__global__ __launch_bounds__(256)
void attn_output(const unsigned short* __restrict__ qkv, const int* __restrict__ len,
                 const unsigned short* __restrict__ sprefix, const float* __restrict__ kprefix,
                 unsigned short* __restrict__ a_bf) {
    const int c = blockIdx.x & (NCH - 1);
    const int bh = blockIdx.x / NCH;
    const int b = bh >> 3, h = bh & 7;
    const int L = len[b];
    const int tid = threadIdx.x;
    const int w = tid >> 6, lane = tid & 63;

    __shared__ __align__(16) unsigned short Qb[64 * 64];    // [i][d] swizzled
    __shared__ __align__(16) unsigned short Kb[64 * 64];    // [j][d] swizzled; reused for out
    __shared__ __align__(16) unsigned short SpT[64 * 64];   // [e][d] swizzled
    __shared__ __align__(16) unsigned short Vt[64 * 64];    // [e][j] swizzled
    __shared__ __align__(16) unsigned short Amb[64 * 64];   // [i][j] swizzled
    __shared__ float zq[64];
    __shared__ float zinv[64];

    const float kspv = kprefix[(size_t)(bh * NCH + c) * 64 + lane];
    const unsigned short* Sp = sprefix + (size_t)(bh * NCH + c) * 4096;

    #pragma unroll 4
    for (int t = 0; t < 16; ++t) {
        const int jj = 4 * t + w;
        const int d = lane;
        const int sglob = c * 64 + jj;
        const unsigned short* base = qkv + (size_t)(b * SS + sglob) * 1536 + h * 64 + d;
        float qv = bf2f(base[0]), kv = bf2f(base[512]);
        float qp = phi_f(qv);
        float kp = (sglob < L) ? phi_f(kv) : 0.f;
        const int swr = (((d >> 3) ^ (jj & 7)) << 3) + (d & 7);   // row-major (jj, d)
        Qb[jj * 64 + swr] = f2bf(qp);
        Kb[jj * 64 + swr] = f2bf(kp);
        const int swt = (((jj >> 3) ^ (d & 7)) << 3) + (jj & 7);  // transposed (d, jj)
        Vt[d * 64 + swt] = base[1024];
        SpT[d * 64 + swt] = Sp[jj * 64 + d];                      // Sp[dstate=jj][e=d]
        float zc = qp * kspv;                                     // Q . kprefix
        #pragma unroll
        for (int off = 32; off; off >>= 1) zc += __shfl_xor(zc, off);
        if (lane == 0) zq[jj] = zc;
    }
    __syncthreads();

    const int frow = w * 16 + (lane & 15);
    const int g = lane >> 4;
    bf16x8 aq[2];
    #pragma unroll
    for (int kk = 0; kk < 2; ++kk)
        aq[kk] = *(const bf16x8*)&Qb[frow * 64 + (((kk * 4 + g) ^ (frow & 7)) << 3)];

    // phase 1: Am = Q K^T
    f32x4 am[4] = {};
    #pragma unroll
    for (int jf = 0; jf < 4; ++jf) {
        int brow = jf * 16 + (lane & 15);
        #pragma unroll
        for (int kk = 0; kk < 2; ++kk) {
            bf16x8 bk = *(const bf16x8*)&Kb[brow * 64 + (((kk * 4 + g) ^ (brow & 7)) << 3)];
            am[jf] = __builtin_amdgcn_mfma_f32_16x16x32_bf16(aq[kk], bk, am[jf], 0, 0, 0);
        }
    }

    // phase 2: mask, z row-sums, Amb store (bf16)
    float zl[4] = {0.f, 0.f, 0.f, 0.f};
    #pragma unroll
    for (int jf = 0; jf < 4; ++jf) {
        #pragma unroll
        for (int r = 0; r < 4; ++r) {
            int i = w * 16 + g * 4 + r;
            int j = jf * 16 + (lane & 15);
            float v = (j <= i) ? am[jf][r] : 0.f;
            zl[r] += v;
            Amb[i * 64 + (((j >> 3) ^ (i & 7)) << 3) + (j & 7)] = f2bf(v);
        }
    }
    #pragma unroll
    for (int r = 0; r < 4; ++r)
        #pragma unroll
        for (int off = 1; off < 16; off <<= 1) zl[r] += __shfl_xor(zl[r], off);
    #pragma unroll
    for (int r = 0; r < 4; ++r) {
        if ((lane & 15) == r) {
            int i = w * 16 + g * 4 + r;
            zinv[i] = 1.f / (zl[r] + zq[i] + ATT_EPS);
        }
    }

    // phase 4: out = Q*SpT^T + Am*Vt^T
    f32x4 oc[4] = {};
    #pragma unroll
    for (int ef = 0; ef < 4; ++ef) {
        int brow = ef * 16 + (lane & 15);
        #pragma unroll
        for (int kk = 0; kk < 2; ++kk) {
            bf16x8 bs = *(const bf16x8*)&SpT[brow * 64 + (((kk * 4 + g) ^ (brow & 7)) << 3)];
            oc[ef] = __builtin_amdgcn_mfma_f32_16x16x32_bf16(aq[kk], bs, oc[ef], 0, 0, 0);
        }
    }
    bf16x8 aam[2];
    #pragma unroll
    for (int kk = 0; kk < 2; ++kk)
        aam[kk] = *(const bf16x8*)&Amb[frow * 64 + (((kk * 4 + g) ^ (frow & 7)) << 3)];
    #pragma unroll
    for (int ef = 0; ef < 4; ++ef) {
        int brow = ef * 16 + (lane & 15);
        #pragma unroll
        for (int kk = 0; kk < 2; ++kk) {
            bf16x8 bv = *(const bf16x8*)&Vt[brow * 64 + (((kk * 4 + g) ^ (brow & 7)) << 3)];
            oc[ef] = __builtin_amdgcn_mfma_f32_16x16x32_bf16(aam[kk], bv, oc[ef], 0, 0, 0);
        }
    }

    __syncthreads();   // all waves done reading Kb -> reuse as out staging
    #pragma unroll
    for (int ef = 0; ef < 4; ++ef) {
        #pragma unroll
        for (int r = 0; r < 4; ++r) {
            int i = w * 16 + g * 4 + r;
            int e = ef * 16 + (lane & 15);
            float zi = zinv[i];
            Kb[i * 64 + (((e >> 3) ^ (i & 7)) << 3) + (e & 7)] = f2bf(oc[ef][r] * zi);
        }
    }
    __syncthreads();
    {
        unsigned short* dst = a_bf + (size_t)(b * SS + c * 64) * 512 + h * 64;
        #pragma unroll
        for (int u = 0; u < 2; ++u) {
            int cid = tid + u * 256;            // chunk id 0..511
            int row = cid >> 3, cb = cid & 7;
            int4 val = *(const int4*)&Kb[row * 64 + ((cb ^ (row & 7)) << 3)];
            *(int4*)(dst + (size_t)row * 512 + cb * 8) = val;
        }
    }
}

// ---------------- residual + LayerNorm (wave per row); add-input bf16 ----------------
template<int ADD, int WB>
__global__ __launch_bounds__(64)
void ln_kernel(const float* __restrict__ hin, const unsigned short* __restrict__ add,
               const float* __restrict__ gw, const float* __restrict__ bw,
               float* __restrict__ hout, unsigned short* __restrict__ hbf) {
    const int row = blockIdx.x;
    const int lane = threadIdx.x;
    float v[8];
    const float* hp = hin + (size_t)row * DD;
    float s = 0.f;
    #pragma unroll
    for (int i = 0; i < 2; ++i) {
        int q = lane + i * 64;
        float4 a = ((const float4*)hp)[q];
        if (ADD) {
            ushort4 bb = ((const ushort4*)(add + (size_t)row * DD))[q];
            a.x += bf2f(bb.x); a.y += bf2f(bb.y); a.z += bf2f(bb.z); a.w += bf2f(bb.w);
        }
        v[i*4+0] = a.x; v[i*4+1] = a.y; v[i*4+2] = a.z; v[i*4+3] = a.w;
        s += a.x + a.y + a.z + a.w;
    }
    #pragma unroll
    for (int off = 32; off; off >>= 1) s += __shfl_xor(s, off);
    float mu = s * (1.f / 512.f);
    float sq = 0.f;
    #pragma unroll
    for (int i = 0; i < 8; ++i) { float d = v[i] - mu; sq += d * d; }
    #pragma unroll
    for (int off = 32; off; off >>= 1) sq += __shfl_xor(sq, off);
    float rs = 1.f / sqrtf(sq * (1.f / 512.f) + LN_EPS);
    #pragma unroll
    for (int i = 0; i < 2; ++i) {
        int q = lane + i * 64;
        float4 gv = ((const float4*)gw)[q];
        float4 bv = ((const float4*)bw)[q];
        float4 o;
        o.x = (v[i*4+0] - mu) * rs * gv.x + bv.x;
        o.y = (v[i*4+1] - mu) * rs * gv.y + bv.y;
        o.z = (v[i*4+2] - mu) * rs * gv.z + bv.z;
        o.w = (v[i*4+3] - mu) * rs * gv.w + bv.w;
        ((float4*)(hout + (size_t)row * DD))[q] = o;
        if (WB) {
            ushort4 ub; ub.x = f2bf(o.x); ub.y = f2bf(o.y); ub.z = f2bf(o.z); ub.w = f2bf(o.w);
            ((ushort4*)(hbf + (size_t)row * DD))[q] = ub;
        }
    }
}

// ---------------- host ----------------
extern "C" void kernel_launch(void* const* d_in, const int* in_sizes, int n_in,
                              void* d_out, int out_size, void* d_ws, size_t ws_size,
                              hipStream_t stream) {
    (void)in_sizes; (void)n_in; (void)out_size; (void)ws_size;
    const int*   x   = (const int*)d_in[0];
    const float* emb = (const float*)d_in[1];
    const float* pe  = (const float*)d_in[2];
    const float* Wq  = (const float*)d_in[3];
    const float* bq  = (const float*)d_in[4];
    const float* Wk  = (const float*)d_in[5];
    const float* bk  = (const float*)d_in[6];
    const float* Wv  = (const float*)d_in[7];
    const float* bv  = (const float*)d_in[8];
    const float* Wo  = (const float*)d_in[9];
    const float* bo  = (const float*)d_in[10];
    const float* W1  = (const float*)d_in[11];
    const float* b1  = (const float*)d_in[12];
    const float* W2  = (const float*)d_in[13];
    const float* b2  = (const float*)d_in[14];
    const float* g1  = (const float*)d_in[15];
    const float* be1 = (const float*)d_in[16];
    const float* g2  = (const float*)d_in[17];
    const float* be2 = (const float*)d_in[18];
    const float* gf  = (const float*)d_in[19];
    const float* bff = (const float*)d_in[20];
    float* out = (float*)d_out;

    char* ws = (char*)d_ws;
    size_t off = 0;
    auto alloc = [&](size_t bytes) -> void* {
        void* p = ws + off; off += (bytes + 255) & ~(size_t)255; return p;
    };
    int* len              = (int*)alloc(16);
    unsigned short* qkv_t = (unsigned short*)alloc((size_t)NLAYER * 1536 * 512 * 2);
    unsigned short* wo_t  = (unsigned short*)alloc((size_t)NLAYER * 512 * 512 * 2);
    unsigned short* w1_t  = (unsigned short*)alloc((size_t)NLAYER * 2048 * 512 * 2);
    unsigned short* w2_t  = (unsigned short*)alloc((size_t)NLAYER * 512 * 2048 * 2);
    float* bqkv           = (float*)alloc((size_t)NLAYER * 1536 * 4);
    float* h              = (float*)alloc((size_t)TT * 512 * 4);
    unsigned short* h_bf  = (unsigned short*)alloc((size_t)TT * 512 * 2);
    unsigned short* qkv   = (unsigned short*)alloc((size_t)TT * 1536 * 2);
    unsigned short* a_bf  = (unsigned short*)alloc((size_t)TT * 512 * 2);
    unsigned short* obuf  = (unsigned short*)alloc((size_t)TT * 512 * 2);
    unsigned short* y1_bf = (unsigned short*)alloc((size_t)TT * 2048 * 2);
    unsigned short* states  = (unsigned short*)alloc((size_t)32 * NCH * 4096 * 2);
    float* ksum           = (float*)alloc((size_t)32 * NCH * 64 * 4);
    unsigned short* sprefix = (unsigned short*)alloc((size_t)32 * NCH * 4096 * 2);
    float* kprefix        = (float*)alloc((size_t)32 * NCH * 64 * 4);

    len_kernel<<<BB, 64, 0, stream>>>(x, len);
    embed_kernel<<<(TT * 128) / 256, 256, 0, stream>>>(x, emb, pe, h, h_bf);

    dim3 tb(256);
    transpose_cvt<<<dim3(16, 16, NLAYER), tb, 0, stream>>>(Wq, qkv_t,             512, 512, (size_t)512*512, (size_t)1536*512);
    transpose_cvt<<<dim3(16, 16, NLAYER), tb, 0, stream>>>(Wk, qkv_t + 512*512,   512, 512, (size_t)512*512, (size_t)1536*512);
    transpose_cvt<<<dim3(16, 16, NLAYER), tb, 0, stream>>>(Wv, qkv_t + 1024*512,  512, 512, (size_t)512*512, (size_t)1536*512);
    transpose_cvt<<<dim3(16, 16, NLAYER), tb, 0, stream>>>(Wo, wo_t,              512, 512, (size_t)512*512, (size_t)512*512);
    transpose_cvt<<<dim3(64, 16, NLAYER), tb, 0, stream>>>(W1, w1_t,              512, 2048, (size_t)512*2048, (size_t)2048*512);
    transpose_cvt<<<dim3(16, 64, NLAYER), tb, 0, stream>>>(W2, w2_t,              2048, 512, (size_t)2048*512, (size_t)512*2048);
    bias_concat<<<(NLAYER * 1536 + 255) / 256, 256, 0, stream>>>(bq, bk, bv, bqkv);

    for (int l = 0; l < NLAYER; ++l) {
        gemm_bt<0,1><<<(TT/128) * (1536/128), 256, 0, stream>>>(
            h_bf, qkv_t + (size_t)l*1536*512, bqkv + l*1536, nullptr, qkv, TT, 1536, 512);
        attn_chunk_sums<<<32 * NCH, 256, 0, stream>>>(qkv, len, states, ksum);
        attn_prefix<<<32 * 16, 256, 0, stream>>>(states, ksum, sprefix, kprefix);
        attn_output<<<32 * NCH, 256, 0, stream>>>(qkv, len, sprefix, kprefix, a_bf);
        gemm_bt<0,1><<<(TT/128) * (512/128), 256, 0, stream>>>(
            a_bf, wo_t + (size_t)l*512*512, bo + l*512, nullptr, obuf, TT, 512, 512);
        ln_kernel<1,1><<<TT, 64, 0, stream>>>(h, obuf, g1 + l*512, be1 + l*512, h, h_bf);
        gemm_bt<1,1><<<(TT/128) * (2048/128), 256, 0, stream>>>(
            h_bf, w1_t + (size_t)l*2048*512, b1 + l*2048, nullptr, y1_bf, TT, 2048, 512);
        gemm_bt<0,1><<<(TT/128) * (512/128), 256, 0, stream>>>(
            y1_bf, w2_t + (size_t)l*512*2048, b2 + l*512, nullptr, obuf, TT, 512, 2048);
        ln_kernel<1,1><<<TT, 64, 0, stream>>>(h, obuf, g2 + l*512, be2 + l*512, h, h_bf);
    }
    ln_kernel<0,0><<<TT, 64, 0, stream>>>(h, nullptr, gf, bff, out, nullptr);
}

// Round 7
// 551.766 us; speedup vs baseline: 1.1638x; 1.0542x over previous
//
#include <hip/hip_runtime.h>
#include <math.h>

#define NLAYER 4
#define BB 4
#define SS 2048
#define DD 512
#define HH 8
#define DH 64
#define FF 2048
#define TT (BB*SS)      // 8192 tokens
#define LCH 64          // attention chunk length
#define NCH (SS/LCH)    // 32 chunks
#define LN_EPS 1e-5f
#define ATT_EPS 1e-6f

typedef __bf16 bf16x8 __attribute__((ext_vector_type(8)));
typedef float  f32x4  __attribute__((ext_vector_type(4)));
typedef float  f32x16 __attribute__((ext_vector_type(16)));

__device__ __forceinline__ unsigned short f2bf(float f) {
    union { float f; unsigned u; } a; a.f = f;
    unsigned u = a.u;
    unsigned r = (u + 0x7FFFu + ((u >> 16) & 1u)) >> 16;   // RNE
    return (unsigned short)r;
}
__device__ __forceinline__ float bf2f(unsigned short s) {
    union { unsigned u; float f; } a; a.u = ((unsigned)s) << 16;
    return a.f;
}
__device__ __forceinline__ float phi_f(float u) {   // elu(u)+1
    return u > 0.f ? u + 1.f : __expf(u);
}

// ---------------- lengths ----------------
__global__ __launch_bounds__(64)
void len_kernel(const int* __restrict__ x, int* __restrict__ len) {
    const int b = blockIdx.x;
    int cnt = 0;
    for (int s = threadIdx.x; s < SS; s += 64) cnt += (x[b * SS + s] != 0);
    #pragma unroll
    for (int off = 32; off; off >>= 1) cnt += __shfl_xor(cnt, off);
    if (threadIdx.x == 0) len[b] = cnt;
}

// ---------------- embedding + positional (bf16 out) ----------------
__global__ __launch_bounds__(256)
void embed_kernel(const int* __restrict__ x, const float* __restrict__ emb,
                  const float* __restrict__ pe, unsigned short* __restrict__ h) {
    int t = blockIdx.x * 256 + threadIdx.x;   // over TT*64 16B slots
    int row = t >> 6, q = t & 63;
    int tok = x[row];
    int s = row & (SS - 1);
    const float4* ep = (const float4*)(emb + (size_t)tok * DD);
    const float4* pp = (const float4*)(pe + (size_t)s * DD);
    float4 e0 = ep[q * 2], e1 = ep[q * 2 + 1];
    float4 p0 = pp[q * 2], p1 = pp[q * 2 + 1];
    ushort4 u0 = make_ushort4(f2bf(e0.x + p0.x), f2bf(e0.y + p0.y),
                              f2bf(e0.z + p0.z), f2bf(e0.w + p0.w));
    ushort4 u1 = make_ushort4(f2bf(e1.x + p1.x), f2bf(e1.y + p1.y),
                              f2bf(e1.z + p1.z), f2bf(e1.w + p1.w));
    size_t base = (size_t)row * DD + q * 8;
    *(ushort4*)(h + base) = u0;
    *(ushort4*)(h + base + 4) = u1;
}

// ---------------- transpose f32[R][C] -> bf16[C][R] ----------------
__global__ __launch_bounds__(256)
void transpose_cvt(const float* __restrict__ src, unsigned short* __restrict__ dst,
                   int R, int C, size_t srcLS, size_t dstLS) {
    __shared__ float tile[32][33];
    const int z = blockIdx.z;
    src += (size_t)z * srcLS;
    dst += (size_t)z * dstLS;
    const int c0 = blockIdx.x * 32, r0 = blockIdx.y * 32;
    const int tx = threadIdx.x & 31, ty = threadIdx.x >> 5;  // ty 0..7
    #pragma unroll
    for (int i = 0; i < 32; i += 8)
        tile[ty + i][tx] = src[(size_t)(r0 + ty + i) * C + c0 + tx];
    __syncthreads();
    #pragma unroll
    for (int i = 0; i < 32; i += 8)
        dst[(size_t)(c0 + ty + i) * R + r0 + tx] = f2bf(tile[tx][ty + i]);
}

__global__ __launch_bounds__(256)
void bias_concat(const float* __restrict__ bq, const float* __restrict__ bk,
                 const float* __restrict__ bv, float* __restrict__ bqkv) {
    int idx = blockIdx.x * 256 + threadIdx.x;
    if (idx >= NLAYER * 1536) return;
    int l = idx / 1536, n = idx % 1536;
    float v = n < 512 ? bq[l * 512 + n] : (n < 1024 ? bk[l * 512 + n - 512] : bv[l * 512 + n - 1024]);
    bqkv[idx] = v;
}

// ---------------- async global->LDS 16B ----------------
__device__ __forceinline__ void gll16(void* lds_ptr, const void* g_ptr) {
    __builtin_amdgcn_global_load_lds(
        (const __attribute__((address_space(1))) void*)g_ptr,
        (__attribute__((address_space(3))) void*)lds_ptr, 16, 0, 0);
}

// ---------------- 128x128 2-phase GEMM, 32x32x16 MFMA inner ----------------
// C[M,N] = A[M,K] * Bt[N,K]^T + bias. 4 waves (2x2), each wave 64x64 output
// as 2x2 32x32 frags. A/B input layout: row = lane%32, k = 8*(lane/32)+j.
// C/D layout (m74/m101 verified): col = lane&31, row = (reg&3)+8*(reg>>2)+4*(lane>>5).
template<int RELU, int WB>
__global__ __launch_bounds__(256, 2)
void gemm_bt(const unsigned short* __restrict__ A, const unsigned short* __restrict__ Bt,
             const float* __restrict__ bias, float* __restrict__ Cf,
             unsigned short* __restrict__ Cb, int M, int N, int K) {
    __shared__ __align__(16) char lds[2 * 2 * 128 * 64 * 2];   // 64 KiB
    const int Nt = N >> 7;
    const int bid = blockIdx.x;
    const int swz = (bid & 7) * ((int)gridDim.x >> 3) + (bid >> 3);
    const int m0 = (swz / Nt) * 128;
    const int n0 = (swz % Nt) * 128;
    const int tid = threadIdx.x;
    const int w = tid >> 6, lane = tid & 63;
    const int wr = w >> 1, wc = w & 1;
    const int srow = lane >> 3, scc = lane & 7;
    const int l32 = lane & 31, khalf = lane >> 5;

    f32x16 acc[2][2] = {};

    auto stage = [&](int buf, int k0) {
        char* base = lds + buf * 32768;
        #pragma unroll
        for (int op = 0; op < 2; ++op) {
            const unsigned short* G = op ? Bt : A;
            const int r0 = op ? n0 : m0;
            char* obase = base + op * 16384;
            #pragma unroll
            for (int i = 0; i < 4; ++i) {
                int ii = w * 4 + i;
                int row = ii * 8 + srow;
                int chunk = scc ^ (row & 7);
                gll16(obase + ii * 1024,
                      G + (size_t)(r0 + row) * K + k0 + chunk * 8);
            }
        }
    };

    stage(0, 0);
    const int nt = K >> 6;
    int buf = 0;
    const int rA = wr * 64 + l32;
    const int rB = wc * 64 + l32;

    for (int kt = 0; kt < nt; ++kt) {
        __syncthreads();
        if (kt + 1 < nt) stage(buf ^ 1, (kt + 1) << 6);
        const char* pA = lds + buf * 32768;
        const char* pB = pA + 16384;
        bf16x8 af[2][4], bfr[2][4];
        #pragma unroll
        for (int mf = 0; mf < 2; ++mf)
            #pragma unroll
            for (int kk = 0; kk < 4; ++kk) {
                int row = rA + mf * 32;
                int c = (kk * 2 + khalf) ^ (row & 7);
                af[mf][kk] = *(const bf16x8*)(pA + row * 128 + c * 16);
            }
        #pragma unroll
        for (int nf = 0; nf < 2; ++nf)
            #pragma unroll
            for (int kk = 0; kk < 4; ++kk) {
                int row = rB + nf * 32;
                int c = (kk * 2 + khalf) ^ (row & 7);
                bfr[nf][kk] = *(const bf16x8*)(pB + row * 128 + c * 16);
            }
        #pragma unroll
        for (int kk = 0; kk < 4; ++kk)
            #pragma unroll
            for (int mf = 0; mf < 2; ++mf)
                #pragma unroll
                for (int nf = 0; nf < 2; ++nf)
                    acc[mf][nf] = __builtin_amdgcn_mfma_f32_32x32x16_bf16(
                        af[mf][kk], bfr[nf][kk], acc[mf][nf], 0, 0, 0);
        buf ^= 1;
    }

    // epilogue: col = lane&31, row = (reg&3)+8*(reg>>2)+4*khalf
    #pragma unroll
    for (int nf = 0; nf < 2; ++nf) {
        int col = n0 + wc * 64 + nf * 32 + l32;
        float bi = bias[col];
        #pragma unroll
        for (int mf = 0; mf < 2; ++mf) {
            int rowb = m0 + wr * 64 + mf * 32 + 4 * khalf;
            #pragma unroll
            for (int reg = 0; reg < 16; ++reg) {
                int row = rowb + (reg & 3) + 8 * (reg >> 2);
                float v = acc[mf][nf][reg] + bi;
                if (RELU) v = v > 0.f ? v : 0.f;
                if (WB) Cb[(size_t)row * N + col] = f2bf(v);
                else    Cf[(size_t)row * N + col] = v;
            }
        }
    }
}

// ---------------- attention pass A (MFMA): states = K^T V (bf16 out), ksum ----------------
__global__ __launch_bounds__(256)
void attn_chunk_sums(const unsigned short* __restrict__ qkv, const int* __restrict__ len,
                     unsigned short* __restrict__ states, float* __restrict__ ksum) {
    const int c = blockIdx.x & (NCH - 1);
    const int bh = blockIdx.x / NCH;
    const int b = bh >> 3, h = bh & 7;
    const int L = len[b];
    const int tid = threadIdx.x;
    const int w = tid >> 6, lane = tid & 63;
    __shared__ __align__(16) unsigned short Kt[64 * 64];   // [d][j], swizzled
    __shared__ __align__(16) unsigned short Vt[64 * 64];   // [e][j], swizzled
    __shared__ float ksumP[4][64];

    float kpart = 0.f;
    #pragma unroll 8
    for (int t = 0; t < 16; ++t) {
        const int jj = 4 * t + w;
        const int d = lane;
        const int sglob = c * 64 + jj;
        const unsigned short* base = qkv + (size_t)(b * SS + sglob) * 1536 + h * 64 + d;
        float kv = bf2f(base[512]);
        float kp = (sglob < L) ? phi_f(kv) : 0.f;
        kpart += kp;
        const int sw = (((jj >> 3) ^ (d & 7)) << 3) + (jj & 7);
        Kt[d * 64 + sw] = f2bf(kp);
        Vt[d * 64 + sw] = base[1024];
    }
    ksumP[w][lane] = kpart;
    __syncthreads();

    const int frow = w * 16 + (lane & 15);   // d-row of output
    const int g = lane >> 4;
    bf16x8 ak[2];
    #pragma unroll
    for (int kk = 0; kk < 2; ++kk)
        ak[kk] = *(const bf16x8*)&Kt[frow * 64 + (((kk * 4 + g) ^ (frow & 7)) << 3)];
    f32x4 oc[4] = {};
    #pragma unroll
    for (int ef = 0; ef < 4; ++ef) {
        int brow = ef * 16 + (lane & 15);
        #pragma unroll
        for (int kk = 0; kk < 2; ++kk) {
            bf16x8 bv = *(const bf16x8*)&Vt[brow * 64 + (((kk * 4 + g) ^ (brow & 7)) << 3)];
            oc[ef] = __builtin_amdgcn_mfma_f32_16x16x32_bf16(ak[kk], bv, oc[ef], 0, 0, 0);
        }
    }
    unsigned short* so = states + (size_t)blockIdx.x * 4096;
    #pragma unroll
    for (int ef = 0; ef < 4; ++ef)
        #pragma unroll
        for (int r = 0; r < 4; ++r) {
            int dd = w * 16 + g * 4 + r;
            int e = ef * 16 + (lane & 15);
            so[dd * 64 + e] = f2bf(oc[ef][r]);
        }
    if (w == 0) {
        float s = ksumP[0][lane] + ksumP[1][lane] + ksumP[2][lane] + ksumP[3][lane];
        ksum[(size_t)blockIdx.x * 64 + lane] = s;
    }
}

// ---------------- attention pass B: exclusive prefix over chunks (bf16 in/out) ----------------
__global__ __launch_bounds__(256)
void attn_prefix(const unsigned short* __restrict__ states, const float* __restrict__ ksum,
                 unsigned short* __restrict__ sprefix, float* __restrict__ kprefix) {
    const int bh = blockIdx.x >> 4;
    const int idx = (blockIdx.x & 15) * 256 + threadIdx.x;
    size_t base = (size_t)bh * NCH * 4096 + idx;
    float run = 0.f;
    #pragma unroll 4
    for (int cc = 0; cc < NCH; ++cc) {
        size_t o = base + (size_t)cc * 4096;
        float v = bf2f(states[o]);
        sprefix[o] = f2bf(run);
        run += v;
    }
    if ((blockIdx.x & 15) == 0 && threadIdx.x < 64) {
        size_t kb = (size_t)bh * NCH * 64 + threadIdx.x;
        float krun = 0.f;
        for (int cc = 0; cc < NCH; ++cc) {
            size_t o = kb + (size_t)cc * 64;
            float v = ksum[o];
            kprefix[o] = krun;
            krun += v;
        }
    }
}

// ---------------- attention pass C (MFMA): intra + inter, write bf16 ----------------
__global__ __launch_bounds__(256)
void attn_output(const unsigned short* __restrict__ qkv, const int* __restrict__ len,
                 const unsigned short* __restrict__ sprefix, const float* __restrict__ kprefix,
                 unsigned short* __restrict__ a_bf) {
    const int c = blockIdx.x & (NCH - 1);
    const int bh = blockIdx.x / NCH;
    const int b = bh >> 3, h = bh & 7;
    const int L = len[b];
    const int tid = threadIdx.x;
    const int w = tid >> 6, lane = tid & 63;

    __shared__ __align__(16) unsigned short Qb[64 * 64];    // [i][d] swizzled
    __shared__ __align__(16) unsigned short Kb[64 * 64];    // [j][d] swizzled; reused for out
    __shared__ __align__(16) unsigned short SpT[64 * 64];   // [e][d] swizzled
    __shared__ __align__(16) unsigned short Vt[64 * 64];    // [e][j] swizzled
    __shared__ __align__(16) unsigned short Amb[64 * 64];   // [i][j] swizzled
    __shared__ float zq[64];
    __shared__ float zinv[64];

    const float kspv = kprefix[(size_t)(bh * NCH + c) * 64 + lane];
    const unsigned short* Sp = sprefix + (size_t)(bh * NCH + c) * 4096;

    #pragma unroll 4
    for (int t = 0; t < 16; ++t) {
        const int jj = 4 * t + w;
        const int d = lane;
        const int sglob = c * 64 + jj;
        const unsigned short* base = qkv + (size_t)(b * SS + sglob) * 1536 + h * 64 + d;
        float qv = bf2f(base[0]), kv = bf2f(base[512]);
        float qp = phi_f(qv);
        float kp = (sglob < L) ? phi_f(kv) : 0.f;
        const int swr = (((d >> 3) ^ (jj & 7)) << 3) + (d & 7);   // row-major (jj, d)
        Qb[jj * 64 + swr] = f2bf(qp);
        Kb[jj * 64 + swr] = f2bf(kp);
        const int swt = (((jj >> 3) ^ (d & 7)) << 3) + (jj & 7);  // transposed (d, jj)
        Vt[d * 64 + swt] = base[1024];
        SpT[d * 64 + swt] = Sp[jj * 64 + d];                      // Sp[dstate=jj][e=d]
        float zc = qp * kspv;                                     // Q . kprefix
        #pragma unroll
        for (int off = 32; off; off >>= 1) zc += __shfl_xor(zc, off);
        if (lane == 0) zq[jj] = zc;
    }
    __syncthreads();

    const int frow = w * 16 + (lane & 15);
    const int g = lane >> 4;
    bf16x8 aq[2];
    #pragma unroll
    for (int kk = 0; kk < 2; ++kk)
        aq[kk] = *(const bf16x8*)&Qb[frow * 64 + (((kk * 4 + g) ^ (frow & 7)) << 3)];

    // phase 1: Am = Q K^T
    f32x4 am[4] = {};
    #pragma unroll
    for (int jf = 0; jf < 4; ++jf) {
        int brow = jf * 16 + (lane & 15);
        #pragma unroll
        for (int kk = 0; kk < 2; ++kk) {
            bf16x8 bk = *(const bf16x8*)&Kb[brow * 64 + (((kk * 4 + g) ^ (brow & 7)) << 3)];
            am[jf] = __builtin_amdgcn_mfma_f32_16x16x32_bf16(aq[kk], bk, am[jf], 0, 0, 0);
        }
    }

    // phase 2: mask, z row-sums, Amb store (bf16)
    float zl[4] = {0.f, 0.f, 0.f, 0.f};
    #pragma unroll
    for (int jf = 0; jf < 4; ++jf) {
        #pragma unroll
        for (int r = 0; r < 4; ++r) {
            int i = w * 16 + g * 4 + r;
            int j = jf * 16 + (lane & 15);
            float v = (j <= i) ? am[jf][r] : 0.f;
            zl[r] += v;
            Amb[i * 64 + (((j >> 3) ^ (i & 7)) << 3) + (j & 7)] = f2bf(v);
        }
    }
    #pragma unroll
    for (int r = 0; r < 4; ++r)
        #pragma unroll
        for (int off = 1; off < 16; off <<= 1) zl[r] += __shfl_xor(zl[r], off);
    #pragma unroll
    for (int r = 0; r < 4; ++r) {
        if ((lane & 15) == r) {
            int i = w * 16 + g * 4 + r;
            zinv[i] = 1.f / (zl[r] + zq[i] + ATT_EPS);
        }
    }

    // phase 4: out = Q*SpT^T + Am*Vt^T
    f32x4 oc[4] = {};
    #pragma unroll
    for (int ef = 0; ef < 4; ++ef) {
        int brow = ef * 16 + (lane & 15);
        #pragma unroll
        for (int kk = 0; kk < 2; ++kk) {
            bf16x8 bs = *(const bf16x8*)&SpT[brow * 64 + (((kk * 4 + g) ^ (brow & 7)) << 3)];
            oc[ef] = __builtin_amdgcn_mfma_f32_16x16x32_bf16(aq[kk], bs, oc[ef], 0, 0, 0);
        }
    }
    bf16x8 aam[2];
    #pragma unroll
    for (int kk = 0; kk < 2; ++kk)
        aam[kk] = *(const bf16x8*)&Amb[frow * 64 + (((kk * 4 + g) ^ (frow & 7)) << 3)];
    #pragma unroll
    for (int ef = 0; ef < 4; ++ef) {
        int brow = ef * 16 + (lane & 15);
        #pragma unroll
        for (int kk = 0; kk < 2; ++kk) {
            bf16x8 bv = *(const bf16x8*)&Vt[brow * 64 + (((kk * 4 + g) ^ (brow & 7)) << 3)];
            oc[ef] = __builtin_amdgcn_mfma_f32_16x16x32_bf16(aam[kk], bv, oc[ef], 0, 0, 0);
        }
    }

    __syncthreads();   // all waves done reading Kb -> reuse as out staging
    #pragma unroll
    for (int ef = 0; ef < 4; ++ef) {
        #pragma unroll
        for (int r = 0; r < 4; ++r) {
            int i = w * 16 + g * 4 + r;
            int e = ef * 16 + (lane & 15);
            float zi = zinv[i];
            Kb[i * 64 + (((e >> 3) ^ (i & 7)) << 3) + (e & 7)] = f2bf(oc[ef][r] * zi);
        }
    }
    __syncthreads();
    {
        unsigned short* dst = a_bf + (size_t)(b * SS + c * 64) * 512 + h * 64;
        #pragma unroll
        for (int u = 0; u < 2; ++u) {
            int cid = tid + u * 256;            // chunk id 0..511
            int row = cid >> 3, cb = cid & 7;
            int4 val = *(const int4*)&Kb[row * 64 + ((cb ^ (row & 7)) << 3)];
            *(int4*)(dst + (size_t)row * 512 + cb * 8) = val;
        }
    }
}

// ---------------- residual + LayerNorm, bf16 residual stream, 4 rows/block ----------------
template<int ADD, int FINAL>
__global__ __launch_bounds__(256)
void ln_kernel(const unsigned short* __restrict__ hin, const unsigned short* __restrict__ add,
               const float* __restrict__ gw, const float* __restrict__ bw,
               unsigned short* __restrict__ hout, float* __restrict__ fout) {
    const int row = blockIdx.x * 4 + (threadIdx.x >> 6);
    const int lane = threadIdx.x & 63;
    const size_t base = (size_t)row * DD + lane * 8;
    float v[8];
    {
        ushort4 a0 = *(const ushort4*)(hin + base);
        ushort4 a1 = *(const ushort4*)(hin + base + 4);
        v[0] = bf2f(a0.x); v[1] = bf2f(a0.y); v[2] = bf2f(a0.z); v[3] = bf2f(a0.w);
        v[4] = bf2f(a1.x); v[5] = bf2f(a1.y); v[6] = bf2f(a1.z); v[7] = bf2f(a1.w);
    }
    if (ADD) {
        ushort4 b0 = *(const ushort4*)(add + base);
        ushort4 b1 = *(const ushort4*)(add + base + 4);
        v[0] += bf2f(b0.x); v[1] += bf2f(b0.y); v[2] += bf2f(b0.z); v[3] += bf2f(b0.w);
        v[4] += bf2f(b1.x); v[5] += bf2f(b1.y); v[6] += bf2f(b1.z); v[7] += bf2f(b1.w);
    }
    float s = 0.f;
    #pragma unroll
    for (int i = 0; i < 8; ++i) s += v[i];
    #pragma unroll
    for (int off = 32; off; off >>= 1) s += __shfl_xor(s, off);
    float mu = s * (1.f / 512.f);
    float sq = 0.f;
    #pragma unroll
    for (int i = 0; i < 8; ++i) { float d = v[i] - mu; sq += d * d; }
    #pragma unroll
    for (int off = 32; off; off >>= 1) sq += __shfl_xor(sq, off);
    float rs = 1.f / sqrtf(sq * (1.f / 512.f) + LN_EPS);
    float4 g0 = ((const float4*)gw)[lane * 2], g1v = ((const float4*)gw)[lane * 2 + 1];
    float4 b0 = ((const float4*)bw)[lane * 2], b1v = ((const float4*)bw)[lane * 2 + 1];
    float gg[8] = {g0.x, g0.y, g0.z, g0.w, g1v.x, g1v.y, g1v.z, g1v.w};
    float bb[8] = {b0.x, b0.y, b0.z, b0.w, b1v.x, b1v.y, b1v.z, b1v.w};
    float o[8];
    #pragma unroll
    for (int i = 0; i < 8; ++i) o[i] = (v[i] - mu) * rs * gg[i] + bb[i];
    if (FINAL) {
        *(float4*)(fout + base)     = make_float4(o[0], o[1], o[2], o[3]);
        *(float4*)(fout + base + 4) = make_float4(o[4], o[5], o[6], o[7]);
    } else {
        *(ushort4*)(hout + base)     = make_ushort4(f2bf(o[0]), f2bf(o[1]), f2bf(o[2]), f2bf(o[3]));
        *(ushort4*)(hout + base + 4) = make_ushort4(f2bf(o[4]), f2bf(o[5]), f2bf(o[6]), f2bf(o[7]));
    }
}

// ---------------- host ----------------
extern "C" void kernel_launch(void* const* d_in, const int* in_sizes, int n_in,
                              void* d_out, int out_size, void* d_ws, size_t ws_size,
                              hipStream_t stream) {
    (void)in_sizes; (void)n_in; (void)out_size; (void)ws_size;
    const int*   x   = (const int*)d_in[0];
    const float* emb = (const float*)d_in[1];
    const float* pe  = (const float*)d_in[2];
    const float* Wq  = (const float*)d_in[3];
    const float* bq  = (const float*)d_in[4];
    const float* Wk  = (const float*)d_in[5];
    const float* bk  = (const float*)d_in[6];
    const float* Wv  = (const float*)d_in[7];
    const float* bv  = (const float*)d_in[8];
    const float* Wo  = (const float*)d_in[9];
    const float* bo  = (const float*)d_in[10];
    const float* W1  = (const float*)d_in[11];
    const float* b1  = (const float*)d_in[12];
    const float* W2  = (const float*)d_in[13];
    const float* b2  = (const float*)d_in[14];
    const float* g1  = (const float*)d_in[15];
    const float* be1 = (const float*)d_in[16];
    const float* g2  = (const float*)d_in[17];
    const float* be2 = (const float*)d_in[18];
    const float* gf  = (const float*)d_in[19];
    const float* bff = (const float*)d_in[20];
    float* out = (float*)d_out;

    char* ws = (char*)d_ws;
    size_t off = 0;
    auto alloc = [&](size_t bytes) -> void* {
        void* p = ws + off; off += (bytes + 255) & ~(size_t)255; return p;
    };
    int* len              = (int*)alloc(16);
    unsigned short* qkv_t = (unsigned short*)alloc((size_t)NLAYER * 1536 * 512 * 2);
    unsigned short* wo_t  = (unsigned short*)alloc((size_t)NLAYER * 512 * 512 * 2);
    unsigned short* w1_t  = (unsigned short*)alloc((size_t)NLAYER * 2048 * 512 * 2);
    unsigned short* w2_t  = (unsigned short*)alloc((size_t)NLAYER * 512 * 2048 * 2);
    float* bqkv           = (float*)alloc((size_t)NLAYER * 1536 * 4);
    unsigned short* h     = (unsigned short*)alloc((size_t)TT * 512 * 2);
    unsigned short* qkv   = (unsigned short*)alloc((size_t)TT * 1536 * 2);
    unsigned short* a_bf  = (unsigned short*)alloc((size_t)TT * 512 * 2);
    unsigned short* obuf  = (unsigned short*)alloc((size_t)TT * 512 * 2);
    unsigned short* y1_bf = (unsigned short*)alloc((size_t)TT * 2048 * 2);
    unsigned short* states  = (unsigned short*)alloc((size_t)32 * NCH * 4096 * 2);
    float* ksum           = (float*)alloc((size_t)32 * NCH * 64 * 4);
    unsigned short* sprefix = (unsigned short*)alloc((size_t)32 * NCH * 4096 * 2);
    float* kprefix        = (float*)alloc((size_t)32 * NCH * 64 * 4);

    len_kernel<<<BB, 64, 0, stream>>>(x, len);
    embed_kernel<<<(TT * 64) / 256, 256, 0, stream>>>(x, emb, pe, h);

    dim3 tb(256);
    transpose_cvt<<<dim3(16, 16, NLAYER), tb, 0, stream>>>(Wq, qkv_t,             512, 512, (size_t)512*512, (size_t)1536*512);
    transpose_cvt<<<dim3(16, 16, NLAYER), tb, 0, stream>>>(Wk, qkv_t + 512*512,   512, 512, (size_t)512*512, (size_t)1536*512);
    transpose_cvt<<<dim3(16, 16, NLAYER), tb, 0, stream>>>(Wv, qkv_t + 1024*512,  512, 512, (size_t)512*512, (size_t)1536*512);
    transpose_cvt<<<dim3(16, 16, NLAYER), tb, 0, stream>>>(Wo, wo_t,              512, 512, (size_t)512*512, (size_t)512*512);
    transpose_cvt<<<dim3(64, 16, NLAYER), tb, 0, stream>>>(W1, w1_t,              512, 2048, (size_t)512*2048, (size_t)2048*512);
    transpose_cvt<<<dim3(16, 64, NLAYER), tb, 0, stream>>>(W2, w2_t,              2048, 512, (size_t)2048*512, (size_t)512*2048);
    bias_concat<<<(NLAYER * 1536 + 255) / 256, 256, 0, stream>>>(bq, bk, bv, bqkv);

    for (int l = 0; l < NLAYER; ++l) {
        gemm_bt<0,1><<<(TT/128) * (1536/128), 256, 0, stream>>>(
            h, qkv_t + (size_t)l*1536*512, bqkv + l*1536, nullptr, qkv, TT, 1536, 512);
        attn_chunk_sums<<<32 * NCH, 256, 0, stream>>>(qkv, len, states, ksum);
        attn_prefix<<<32 * 16, 256, 0, stream>>>(states, ksum, sprefix, kprefix);
        attn_output<<<32 * NCH, 256, 0, stream>>>(qkv, len, sprefix, kprefix, a_bf);
        gemm_bt<0,1><<<(TT/128) * (512/128), 256, 0, stream>>>(
            a_bf, wo_t + (size_t)l*512*512, bo + l*512, nullptr, obuf, TT, 512, 512);
        ln_kernel<1,0><<<TT/4, 256, 0, stream>>>(h, obuf, g1 + l*512, be1 + l*512, h, nullptr);
        gemm_bt<1,1><<<(TT/128) * (2048/128), 256, 0, stream>>>(
            h, w1_t + (size_t)l*2048*512, b1 + l*2048, nullptr, y1_bf, TT, 2048, 512);
        gemm_bt<0,1><<<(TT/128) * (512/128), 256, 0, stream>>>(
            y1_bf, w2_t + (size_t)l*512*2048, b2 + l*512, nullptr, obuf, TT, 512, 2048);
        ln_kernel<1,0><<<TT/4, 256, 0, stream>>>(h, obuf, g2 + l*512, be2 + l*512, h, nullptr);
    }
    ln_kernel<0,1><<<TT/4, 256, 0, stream>>>(h, nullptr, gf, bff, nullptr, out);
}